// Round 3
// baseline (144.268 us; speedup 1.0000x reference)
//
#include <hip/hip_runtime.h>

// DAS beamforming: out[b,z,x,k] = sum_c lerp(rf[b,c], delay(b,c,z,x))[k]
// Round 3: - rf pre-converted to fp16 in ws: halves LDS gather bytes, staging
//            traffic, and LDS footprint (16 KiB/channel slice)
//          - 2 blocks/CU (512 blocks, C_PER_BLOCK=16, N_CHUNKS=8): barrier
//            drains of one block overlap with compute of the other
//          - partials (8 chunks) in ws, summed by reduce kernel (no atomics)
// Fixed harness overhead (~45 us: 268 MB ws re-poison fill + input restore)
// dominates the graph time; das itself targets ~12 us.

#define NBATCH 2
#define NC 128
#define NS 2048
#define NK 4
#define NM 65536                              // Nz*Nx pixels per batch

#define THREADS 1024
#define PX_PER_THREAD 2
#define PX_PER_BLOCK (THREADS * PX_PER_THREAD)   // 2048
#define C_PER_BLOCK 16
#define N_CHUNKS (NC / C_PER_BLOCK)           // 8
#define N_TILES (NM / PX_PER_BLOCK)           // 32
#define NBLOCKS (NBATCH * N_TILES * N_CHUNKS) // 512 = 2 blocks/CU
#define SLICE_HALFS (NS * NK)                 // 8192 halves = 16 KiB / channel

#define RF_ELEMS (NBATCH * NC * NS * NK)      // 2,097,152
#define RF_HALF_BYTES ((size_t)RF_ELEMS * 2)  // 4 MiB
#define PART_BYTES ((size_t)N_CHUNKS * NBATCH * NM * NK * 4)  // 16.8 MB

typedef __attribute__((ext_vector_type(4))) _Float16 half4;

// ---- rf fp32 -> fp16 (runs every launch; ws is re-poisoned) ----
__global__ __launch_bounds__(256) void cvt_kernel(const float4* __restrict__ in,
                                                  half4* __restrict__ out) {
    const int i = blockIdx.x * 256 + threadIdx.x;
    const float4 v = in[i];
    half4 h;
    h.x = (_Float16)v.x; h.y = (_Float16)v.y;
    h.z = (_Float16)v.z; h.w = (_Float16)v.w;
    out[i] = h;
}

// Stage one channel slice (16 KiB) global->LDS async: exactly one 16 B
// load per thread (1024 threads), lane-sequential LDS dest as HW requires.
__device__ __forceinline__ void stage_channel(const _Float16* slice,
                                              _Float16* lbuf, int t) {
    __builtin_amdgcn_global_load_lds(
        (const __attribute__((address_space(1))) void*)(slice + t * 8),
        (__attribute__((address_space(3))) void*)(lbuf + t * 8),
        16, 0, 0);
}

__global__ __launch_bounds__(THREADS, 8) void das_kernel(
    const _Float16* __restrict__ rfh, const float* __restrict__ g,
    const float* __restrict__ pr, const float* __restrict__ p,
    float* __restrict__ part)
{
    __shared__ alignas(16) _Float16 sbuf[2][SLICE_HALFS];   // 2 x 16 KiB

    const int bid   = blockIdx.x;
    const int chunk = bid & (N_CHUNKS - 1);
    const int tile  = (bid >> 3) & (N_TILES - 1);
    const int b     = bid >> 8;
    const int t     = threadIdx.x;
    const int px0   = tile * PX_PER_BLOCK;

    const float c0v = p[b * 4 + 0];
    const float fsv = p[b * 4 + 1];
    const float t0v = p[b * 4 + 2];
    const float scale = fsv / c0v;            // samples per meter
    const float sb0   = scale * t0v;

    float gx[PX_PER_THREAD], gy[PX_PER_THREAD], gzv[PX_PER_THREAD], sbase[PX_PER_THREAD];
#pragma unroll
    for (int j = 0; j < PX_PER_THREAD; ++j) {
        const int m = px0 + j * THREADS + t;
        const float* gp = g + ((size_t)b * NM + m) * 3;
        gx[j]  = gp[0];
        gy[j]  = gp[1];
        gzv[j] = gp[2];
        sbase[j] = sb0 + scale * gzv[j];      // fs*(t0 + d_tx)/c0 hoisted
    }

    float4 acc[PX_PER_THREAD];
#pragma unroll
    for (int j = 0; j < PX_PER_THREAD; ++j) acc[j] = make_float4(0.f, 0.f, 0.f, 0.f);

    const int ch0 = chunk * C_PER_BLOCK;
    const _Float16* slice0 = rfh + (size_t)(b * NC + ch0) * SLICE_HALFS;

    stage_channel(slice0, &sbuf[0][0], t);

    for (int cc = 0; cc < C_PER_BLOCK; ++cc) {
        // vmcnt(0)+barrier: drains the stage into sbuf[cc&1] and protects
        // sbuf[(cc+1)&1] from overwrite while still being read.
        __syncthreads();
        if (cc + 1 < C_PER_BLOCK)
            stage_channel(slice0 + (size_t)(cc + 1) * SLICE_HALFS,
                          &sbuf[(cc + 1) & 1][0], t);  // in flight during compute

        const _Float16* lb = &sbuf[cc & 1][0];
        const float* prp = pr + ((size_t)(b * NC + ch0 + cc)) * 3;
        const float prx = prp[0], pry = prp[1], prz = prp[2];

#pragma unroll
        for (int j = 0; j < PX_PER_THREAD; ++j) {
            const float dx = gx[j]  - prx;
            const float dy = gy[j]  - pry;
            const float dz = gzv[j] - prz;
            const float drx = __builtin_amdgcn_sqrtf(fmaf(dx, dx, fmaf(dy, dy, dz * dz)));
            float s = fmaf(scale, drx, sbase[j]);         // fractional sample index
            s = fminf(fmaxf(s, 0.0f), (float)(NS - 1));   // clamp
            const float fi = fminf(floorf(s), (float)(NS - 2));
            const float w  = s - fi;
            const float wm = 1.0f - w;
            const int i0 = (int)fi;
            // y0 = samples[i0][0:4], y1 = samples[i0+1][0:4]: adjacent 8 B
            const half4 y0 = *(const half4*)(lb + i0 * 4);
            const half4 y1 = *(const half4*)(lb + i0 * 4 + 4);
            acc[j].x = fmaf((float)y0.x, wm, fmaf((float)y1.x, w, acc[j].x));
            acc[j].y = fmaf((float)y0.y, wm, fmaf((float)y1.y, w, acc[j].y));
            acc[j].z = fmaf((float)y0.z, wm, fmaf((float)y1.z, w, acc[j].z));
            acc[j].w = fmaf((float)y0.w, wm, fmaf((float)y1.w, w, acc[j].w));
        }
    }

    // partial[chunk][b][m] as float4 — disjoint per block, plain stores
    float4* pw = (float4*)part + (size_t)(chunk * NBATCH + b) * NM;
#pragma unroll
    for (int j = 0; j < PX_PER_THREAD; ++j) {
        const int m = px0 + j * THREADS + t;
        pw[m] = acc[j];
    }
}

// out[i] = sum over 8 chunk partials; i indexes float4 over [B*NM)
__global__ __launch_bounds__(256) void reduce_kernel(
    const float4* __restrict__ part, float4* __restrict__ out)
{
    const int i = blockIdx.x * 256 + threadIdx.x;
    const size_t stride = (size_t)NBATCH * NM;
    float4 a = part[i];
#pragma unroll
    for (int c = 1; c < N_CHUNKS; ++c) {
        const float4 v = part[c * stride + i];
        a.x += v.x; a.y += v.y; a.z += v.z; a.w += v.w;
    }
    out[i] = a;
}

// ---- fallback (ws too small): fp32 atomic path, memset + single kernel ----
__global__ __launch_bounds__(1024) void das_atomic_f32(
    const float* __restrict__ rf, const float* __restrict__ g,
    const float* __restrict__ pr, const float* __restrict__ p,
    float* __restrict__ out)
{
    const int bid   = blockIdx.x;
    const int chunk = bid & 3;
    const int tile  = (bid >> 2) & 31;
    const int b     = bid >> 7;
    const int t     = threadIdx.x;
    const int m     = tile * 2048 + t;
    const float scale = p[b * 4 + 1] / p[b * 4 + 0];
    const float sb0   = scale * p[b * 4 + 2];
    for (int jj = 0; jj < 2; ++jj) {
        const int mm = m + jj * 1024;
        const float* gp = g + ((size_t)b * NM + mm) * 3;
        const float gxv = gp[0], gyv = gp[1], gzz = gp[2];
        float4 acc = make_float4(0.f, 0.f, 0.f, 0.f);
        for (int cc = 0; cc < 32; ++cc) {
            const int ch = chunk * 32 + cc;
            const float* prp = pr + ((size_t)b * NC + ch) * 3;
            const float dx = gxv - prp[0], dy = gyv - prp[1], dz = gzz - prp[2];
            float s = fmaf(scale, __builtin_amdgcn_sqrtf(fmaf(dx,dx,fmaf(dy,dy,dz*dz))) + gzz, sb0);
            s = fminf(fmaxf(s, 0.0f), (float)(NS - 1));
            const float fi = fminf(floorf(s), (float)(NS - 2));
            const float w = s - fi, wm = 1.0f - w;
            const float4* sl = (const float4*)(rf + (size_t)(b * NC + ch) * NS * NK);
            const float4 y0 = sl[(int)fi], y1 = sl[(int)fi + 1];
            acc.x = fmaf(y0.x, wm, fmaf(y1.x, w, acc.x));
            acc.y = fmaf(y0.y, wm, fmaf(y1.y, w, acc.y));
            acc.z = fmaf(y0.z, wm, fmaf(y1.z, w, acc.z));
            acc.w = fmaf(y0.w, wm, fmaf(y1.w, w, acc.w));
        }
        float* op = out + ((size_t)b * NM + mm) * NK;
        atomicAdd(op + 0, acc.x); atomicAdd(op + 1, acc.y);
        atomicAdd(op + 2, acc.z); atomicAdd(op + 3, acc.w);
    }
}

extern "C" void kernel_launch(void* const* d_in, const int* in_sizes, int n_in,
                              void* d_out, int out_size, void* d_ws, size_t ws_size,
                              hipStream_t stream) {
    (void)in_sizes; (void)n_in;
    const float* rf = (const float*)d_in[0];
    const float* g  = (const float*)d_in[1];
    const float* pr = (const float*)d_in[2];
    const float* p  = (const float*)d_in[3];
    float* out = (float*)d_out;

    const size_t need = RF_HALF_BYTES + PART_BYTES;   // ~21 MB
    if (ws_size >= need) {
        _Float16* rfh = (_Float16*)d_ws;
        float* part = (float*)((char*)d_ws + RF_HALF_BYTES);
        cvt_kernel<<<RF_ELEMS / 4 / 256, 256, 0, stream>>>((const float4*)rf,
                                                           (half4*)rfh);
        das_kernel<<<NBLOCKS, THREADS, 0, stream>>>(rfh, g, pr, p, part);
        reduce_kernel<<<(NBATCH * NM) / 256, 256, 0, stream>>>((const float4*)part,
                                                               (float4*)out);
    } else {
        hipMemsetAsync(d_out, 0, (size_t)out_size * sizeof(float), stream);
        das_atomic_f32<<<256, 1024, 0, stream>>>(rf, g, pr, p, out);
    }
}